// Round 13
// baseline (289.294 us; speedup 1.0000x reference)
//
#include <hip/hip_runtime.h>
#include <stdint.h>

constexpr int Bsz = 2;
constexpr int Ssz = 2048;
constexpr int Hid = 2048;
constexpr int NHd = 16;
constexpr int Hd  = 128;
constexpr int Mrows = Bsz * Ssz;                 // 4096

typedef __bf16 bf16;
typedef __bf16 bf16x8 __attribute__((ext_vector_type(8)));
typedef __bf16 bf16x4 __attribute__((ext_vector_type(4)));
typedef float  f32x4  __attribute__((ext_vector_type(4)));
typedef float  f32x16 __attribute__((ext_vector_type(16)));

__device__ __forceinline__ void gload_lds16(const bf16* g, bf16* l) {
  __builtin_amdgcn_global_load_lds((const __attribute__((address_space(1))) void*)g,
                                   (__attribute__((address_space(3))) void*)l, 16, 0, 0);
}

__device__ __forceinline__ uint32_t pkbf(bf16 a, bf16 b) {
  union { bf16 hh[2]; uint32_t u; } x;
  x.hh[0] = a; x.hh[1] = b;
  return x.u;
}
__device__ __forceinline__ uint32_t pkff(float a, float b) {
  return pkbf((bf16)a, (bf16)b);
}

// ---------------- f32 -> bf16 bulk convert (4 elems/thread) ----------------
__global__ void k_cvt(const float* __restrict__ in, bf16* __restrict__ out, int n4) {
  int i = blockIdx.x * blockDim.x + threadIdx.x;
  if (i >= n4) return;
  float4 v = ((const float4*)in)[i];
  bf16x4 o = { (bf16)v.x, (bf16)v.y, (bf16)v.z, (bf16)v.w };
  ((bf16x4*)out)[i] = o;
}

// ------- transpose 4 weights [K][N] f32 -> [N][K] bf16, vectorized ---------
__global__ void k_wtrans(const float* __restrict__ w0, const float* __restrict__ w1,
                         const float* __restrict__ w2, const float* __restrict__ w3,
                         bf16* __restrict__ out) {
  __shared__ float tile[64][65];
  const int z = blockIdx.z;
  const float* w = (z == 0) ? w0 : (z == 1) ? w1 : (z == 2) ? w2 : w3;
  bf16* o = out + (size_t)z * Hid * Hid;
  const int n0 = blockIdx.x * 64, k0 = blockIdx.y * 64;
  const int tid = threadIdx.x;
  {
    const int row = tid >> 4, col = (tid & 15) * 4;
#pragma unroll
    for (int i = 0; i < 4; i++) {
      float4 v = *(const float4*)&w[(size_t)(k0 + row + i * 16) * Hid + n0 + col];
      tile[row + i * 16][col + 0] = v.x;
      tile[row + i * 16][col + 1] = v.y;
      tile[row + i * 16][col + 2] = v.z;
      tile[row + i * 16][col + 3] = v.w;
    }
  }
  __syncthreads();
  {
    const int n = tid >> 2, ks = (tid & 3) * 16;
    union { bf16x8 v[2]; bf16 e[16]; } pk;
#pragma unroll
    for (int j = 0; j < 16; j++) pk.e[j] = (bf16)tile[ks + j][n];
    bf16* op = &o[(size_t)(n0 + n) * Hid + k0 + ks];
    *(bf16x8*)op = pk.v[0];
    *(bf16x8*)(op + 8) = pk.v[1];
  }
}

// ---- swizzled-LDS fragment read: element (row,k) lives at byte
//      row*128 + (((k>>3) ^ (row&7))<<4) + (k&7)*2
__device__ __forceinline__ bf16x8 rdfrag(const bf16* t, int row, int kslot) {
  return *(const bf16x8*)((const char*)t + row * 128 + (((kslot ^ (row & 7)) & 7) << 4));
}

// ---- stage a 128-row x 64-col bf16 slice (16 KB): 2 gload_lds per thread,
//      source pre-inverse-swizzled so reads use rdfrag (rule #21)
__device__ __forceinline__ void stage_half(const bf16* g, bf16* l, int w, int lane) {
  const int rsub = lane >> 3;
  const int slot = (lane & 7) ^ rsub;
#pragma unroll
  for (int j = 0; j < 2; ++j) {
    const int blk = w * 2 + j;
    gload_lds16(g + (size_t)(blk * 8 + rsub) * Hid + slot * 8, l + blk * 512);
  }
}

#define PH_BAR() __builtin_amdgcn_s_barrier()

// ======================= m201-port QKV GEMM =================================
// 256x256 tile, BK=64, 8 waves (2m x 4n), per-wave 128x64, acc[8][4].
// LDS 128 KB: smA/smB [slot][half][128][64]. 4 phases/K-tile (one acc
// quadrant x 16 MFMA), double barrier per phase, counted vmcnt(4) at
// phases 4/8 only. Stage rotation (1 half per phase, earliest-safe):
//   ph1 (u+1).A0  ph2 (u+1).A1  ph3 (u+2).B0  ph4 (u+2).B1 +vmcnt(4)
//   ph5 (u+2).A0  ph6 (u+2).A1  ph7 (u+3).B0  ph8 (u+3).B1 +vmcnt(4)
__global__ __launch_bounds__(512, 1) void k_qkv(const bf16* __restrict__ A,
                                                const bf16* __restrict__ Bt,
                                                const float* __restrict__ biasq,
                                                const float* __restrict__ biask,
                                                const float* __restrict__ biasv,
                                                bf16* __restrict__ Qo, bf16* __restrict__ Ko,
                                                bf16* __restrict__ Vo) {
  constexpr int KK = Hid;
  constexpr int NT = KK / 64;            // 32 K-tiles
  __shared__ bf16 smA[2][2][128 * 64];   // 64 KB
  __shared__ bf16 smB[2][2][128 * 64];   // 64 KB
  // T1: grid 24n x 16m = 384; 8 chunks of 4m x 12n, bijective
  const int hw = blockIdx.y * gridDim.x + blockIdx.x;
  const int chunk = hw & 7, within = hw >> 3;
  const int mt = (chunk & 3) * 4 + (within & 3);
  const int nt = (chunk >> 2) * 12 + (within >> 2);
  const int m0 = mt * 256, n0 = nt * 256;
  const int tid = threadIdx.x, lane = tid & 63, w = tid >> 6;
  const int wm = w >> 2, wn = w & 3;
  const int frow = lane & 15, a4 = lane >> 4;
  const bf16* Ag = A + (size_t)m0 * KK;
  const bf16* Bg = Bt + (size_t)n0 * KK;
  const int bbase = (wn & 1) * 64;       // wave's col base within its B-half
  f32x4 acc[8][4] = {};

#define STG_A(v, half) stage_half(Ag + (size_t)(half) * 128 * KK + (size_t)(v) * 64, \
                                  smA[(v) & 1][half], w, lane)
#define STG_B(v, half) stage_half(Bg + (size_t)(half) * 128 * KK + (size_t)(v) * 64, \
                                  smB[(v) & 1][half], w, lane)
#define PH_OPEN()                                        \
  PH_BAR();                                              \
  asm volatile("s_waitcnt lgkmcnt(0)" ::: "memory");     \
  __builtin_amdgcn_sched_barrier(0);                     \
  __builtin_amdgcn_s_setprio(1)
#define PH_CLOSE() __builtin_amdgcn_s_setprio(0)

  // ---- prologue: t0 all 4 halves + t1.B0,B1 (12 loads); complete t0
  STG_A(0, 0); STG_A(0, 1); STG_B(0, 0); STG_B(0, 1);
  STG_B(1, 0); STG_B(1, 1);
  asm volatile("s_waitcnt vmcnt(4)" ::: "memory");
  __builtin_amdgcn_sched_barrier(0);
  __builtin_amdgcn_s_barrier();

  for (int t = 0; t < NT / 2; ++t) {
    const int u = 2 * t;
    const bool more = (u + 2) < NT;      // NT even: u+2<NT <=> u+3<NT
    bf16x8 afL[4][2], afH[4][2], bfL[2][2], bfH[2][2];
#pragma unroll 1
    for (int half = 0; half < 2; ++half) {   // half=0: tile u (ph1-4); half=1: u+1 (ph5-8)
      const int kt = u + half;
      const bf16* Ah = smA[kt & 1][wm];
      const bf16* Bh = smB[kt & 1][wn >> 1];
      // ======== q0: read afL(8) + bfL(4); stage
#pragma unroll
      for (int f = 0; f < 4; ++f)
#pragma unroll
        for (int kk = 0; kk < 2; ++kk)
          afL[f][kk] = rdfrag(Ah, f * 16 + frow, kk * 4 + a4);
#pragma unroll
      for (int f = 0; f < 2; ++f)
#pragma unroll
        for (int kk = 0; kk < 2; ++kk)
          bfL[f][kk] = rdfrag(Bh, bbase + f * 16 + frow, kk * 4 + a4);
      if (half == 0)            STG_A(u + 1, 0);          // ph1
      else if (more)            STG_A(u + 2, 0);          // ph5
      asm volatile("s_waitcnt lgkmcnt(8)" ::: "memory");
      PH_OPEN();
#pragma unroll
      for (int f = 0; f < 4; ++f)
#pragma unroll
        for (int n = 0; n < 2; ++n)
#pragma unroll
          for (int kk = 0; kk < 2; ++kk)
            acc[f][n] = __builtin_amdgcn_mfma_f32_16x16x32_bf16(
                afL[f][kk], bfL[n][kk], acc[f][n], 0, 0, 0);
      PH_CLOSE();
      PH_BAR();
      // ======== q1: read bfH(4); stage
#pragma unroll
      for (int f = 0; f < 2; ++f)
#pragma unroll
        for (int kk = 0; kk < 2; ++kk)
          bfH[f][kk] = rdfrag(Bh, bbase + 32 + f * 16 + frow, kk * 4 + a4);
      if (half == 0)            STG_A(u + 1, 1);          // ph2
      else if (more)            STG_A(u + 2, 1);          // ph6
      PH_OPEN();
#pragma unroll
      for (int f = 0; f < 4; ++f)
#pragma unroll
        for (int n = 0; n < 2; ++n)
#pragma unroll
          for (int kk = 0; kk < 2; ++kk)
            acc[f][2 + n] = __builtin_amdgcn_mfma_f32_16x16x32_bf16(
                afL[f][kk], bfH[n][kk], acc[f][2 + n], 0, 0, 0);
      PH_CLOSE();
      PH_BAR();
      // ======== q2: read afH(8); stage
#pragma unroll
      for (int f = 0; f < 4; ++f)
#pragma unroll
        for (int kk = 0; kk < 2; ++kk)
          afH[f][kk] = rdfrag(Ah, 64 + f * 16 + frow, kk * 4 + a4);
      if (more) { if (half == 0) STG_B(u + 2, 0);          // ph3
                  else           STG_B(u + 3, 0); }        // ph7
      PH_OPEN();
#pragma unroll
      for (int f = 0; f < 4; ++f)
#pragma unroll
        for (int n = 0; n < 2; ++n)
#pragma unroll
          for (int kk = 0; kk < 2; ++kk)
            acc[4 + f][n] = __builtin_amdgcn_mfma_f32_16x16x32_bf16(
                afH[f][kk], bfL[n][kk], acc[4 + f][n], 0, 0, 0);
      PH_CLOSE();
      PH_BAR();
      // ======== q3: no reads; stage; counted wait
      if (more) { if (half == 0) STG_B(u + 2, 1);          // ph4
                  else           STG_B(u + 3, 1); }        // ph8
      PH_OPEN();
#pragma unroll
      for (int f = 0; f < 4; ++f)
#pragma unroll
        for (int n = 0; n < 2; ++n)
#pragma unroll
          for (int kk = 0; kk < 2; ++kk)
            acc[4 + f][2 + n] = __builtin_amdgcn_mfma_f32_16x16x32_bf16(
                afH[f][kk], bfH[n][kk], acc[4 + f][2 + n], 0, 0, 0);
      PH_CLOSE();
      if (half == 0) {
        if (more) { asm volatile("s_waitcnt vmcnt(4)" ::: "memory"); }
        else      { asm volatile("s_waitcnt vmcnt(0)" ::: "memory"); }
        __builtin_amdgcn_sched_barrier(0);
      } else if (more) {
        asm volatile("s_waitcnt vmcnt(4)" ::: "memory");
        __builtin_amdgcn_sched_barrier(0);
      }
      PH_BAR();
    }
  }
#undef STG_A
#undef STG_B
#undef PH_OPEN
#undef PH_CLOSE
  // ---- epilogue: per-wave rows [m0+wm*128,+128) x cols [n0+wn*64,+64)
  const int z = n0 >> 11;                // BN=256 divides 2048: single z
  const float* bias = (z == 0) ? biasq : (z == 1) ? biask : biasv;
  bf16* o = (z == 0) ? Qo : (z == 1) ? Ko : Vo;
  const float oscale = (z == 1) ? (float)(0.08838834764831845 * 1.4426950408889634) : 1.0f;
#pragma unroll
  for (int nf = 0; nf < 4; ++nf) {
    const int col = n0 + wn * 64 + nf * 16 + frow;
    const float bb_ = bias[col & 2047];
    const int h = (col >> 7) & 15, hd = col & (Hd - 1);
#pragma unroll
    for (int mf = 0; mf < 8; ++mf) {
#pragma unroll
      for (int r = 0; r < 4; ++r) {
        const int row = m0 + wm * 128 + mf * 16 + a4 * 4 + r;
        const int bb = row >> 11, ss = row & (Ssz - 1);
        o[(((size_t)bb * NHd + h) * Ssz + ss) * Hd + hd] = (bf16)((acc[mf][nf][r] + bb_) * oscale);
      }
    }
  }
}

// ---- output projection: 256x128 tile, BK=64, per-wave 128x32, 2 phases/
//      K-tile, A dbuf + B triple-buffer, counted vmcnt(2) boundary only.
template <int CHM, int CHN>
__global__ __launch_bounds__(512, 1) void k_gemm(const bf16* __restrict__ A,
                                                 const bf16* __restrict__ Bt,
                                                 float* __restrict__ Fo) {
  constexpr int KK = Hid;
  constexpr int NT = KK / 64;
  __shared__ bf16 smA[2][256 * 64];    // 64 KB
  __shared__ bf16 smB[3][128 * 64];    // 48 KB
  const int hw = blockIdx.y * gridDim.x + blockIdx.x;
  const int chunk = hw & 7, within = hw >> 3;
  const int chunk_rows = gridDim.y / CHM;
  const int cr = chunk % chunk_rows, cc = chunk / chunk_rows;
  const int mt = cr * CHM + within % CHM;
  const int nt = cc * CHN + within / CHM;
  const int m0 = mt * 256, n0 = nt * 128;
  const int tid = threadIdx.x, lane = tid & 63, w = tid >> 6;
  const int wm = w >> 2, wn = w & 3;
  const int frow = lane & 15, a4 = lane >> 4;
  const bf16* Ag = A + (size_t)m0 * KK;
  const bf16* Bg = Bt + (size_t)n0 * KK;
  f32x4 acc[8][2] = {};
  stage_half(Ag,                    smA[0],            w, lane);
  stage_half(Ag + (size_t)128 * KK, smA[0] + 128 * 64, w, lane);
  stage_half(Bg,                    smB[0],            w, lane);
  stage_half(Bg + 64,               smB[1],            w, lane);
  asm volatile("s_waitcnt vmcnt(2)" ::: "memory");
  __builtin_amdgcn_sched_barrier(0);
  __builtin_amdgcn_s_barrier();
  for (int kt = 0; kt < NT; ++kt) {
    const bf16* At  = smA[kt & 1];
    const bf16* Btl = smB[kt % 3];
    const bool more1 = (kt + 1) < NT;
    const bool more2 = (kt + 2) < NT;
    bf16x8 afA[4][2], afB[4][2], bfr[2][2];
#pragma unroll
    for (int f = 0; f < 4; ++f)
#pragma unroll
      for (int kk = 0; kk < 2; ++kk)
        afA[f][kk] = rdfrag(At, wm * 128 + f * 16 + frow, kk * 4 + a4);
#pragma unroll
    for (int nf = 0; nf < 2; ++nf)
#pragma unroll
      for (int kk = 0; kk < 2; ++kk)
        bfr[nf][kk] = rdfrag(Btl, wn * 32 + nf * 16 + frow, kk * 4 + a4);
    if (more1) {
      bf16* As2 = smA[(kt + 1) & 1];
      const size_t kn = (size_t)(kt + 1) * 64;
      stage_half(Ag + kn,                    As2,            w, lane);
      stage_half(Ag + (size_t)128 * KK + kn, As2 + 128 * 64, w, lane);
    }
    PH_BAR();
    __builtin_amdgcn_s_setprio(1);
#pragma unroll
    for (int f = 0; f < 4; ++f)
#pragma unroll
      for (int nf = 0; nf < 2; ++nf)
#pragma unroll
        for (int kk = 0; kk < 2; ++kk)
          acc[f][nf] = __builtin_amdgcn_mfma_f32_16x16x32_bf16(
              afA[f][kk], bfr[nf][kk], acc[f][nf], 0, 0, 0);
    __builtin_amdgcn_s_setprio(0);
    __builtin_amdgcn_s_barrier();
#pragma unroll
    for (int f = 0; f < 4; ++f)
#pragma unroll
      for (int kk = 0; kk < 2; ++kk)
        afB[f][kk] = rdfrag(At, wm * 128 + 64 + f * 16 + frow, kk * 4 + a4);
    if (more2) stage_half(Bg + (size_t)(kt + 2) * 64, smB[(kt + 2) % 3], w, lane);
    PH_BAR();
    __builtin_amdgcn_s_setprio(1);
#pragma unroll
    for (int f = 0; f < 4; ++f)
#pragma unroll
      for (int nf = 0; nf < 2; ++nf)
#pragma unroll
        for (int kk = 0; kk < 2; ++kk)
          acc[4 + f][nf] = __builtin_amdgcn_mfma_f32_16x16x32_bf16(
              afB[f][kk], bfr[nf][kk], acc[4 + f][nf], 0, 0, 0);
    __builtin_amdgcn_s_setprio(0);
    if (more1) {
      if (more2) { asm volatile("s_waitcnt vmcnt(2)" ::: "memory"); }
      else       { asm volatile("s_waitcnt vmcnt(0)" ::: "memory"); }
      __builtin_amdgcn_sched_barrier(0);
    }
    __builtin_amdgcn_s_barrier();
  }
#pragma unroll
  for (int mf = 0; mf < 8; ++mf)
#pragma unroll
    for (int nf = 0; nf < 2; ++nf) {
      const int col = n0 + wn * 32 + nf * 16 + frow;
#pragma unroll
      for (int r = 0; r < 4; ++r) {
        const int row = m0 + wm * 128 + mf * 16 + a4 * 4 + r;
        Fo[(size_t)row * Hid + col] = acc[mf][nf][r];
      }
    }
}

// ---------------- RoPE (neox) on K only, in place -------------------------
__global__ void k_rope(bf16* __restrict__ Kk, const int* __restrict__ pos) {
  const int idx = blockIdx.x * 256 + threadIdx.x;   // (bh, s, i) i fastest
  const int i = idx & 63;
  const int s = (idx >> 6) & (Ssz - 1);
  const int bh = idx >> 17;
  const int b = bh >> 4;
  const float p = (float)pos[b * Ssz + s];
  const float f = p * exp2f(-(float)i * 0.20762050593046014f); // log2(1e4)/64
  float sn, cs;
  sincosf(f, &sn, &cs);
  const size_t base = ((size_t)bh * Ssz + s) * Hd;
  float x1 = (float)Kk[base + i], x2 = (float)Kk[base + i + 64];
  Kk[base + i]      = (bf16)(x1 * cs - x2 * sn);
  Kk[base + i + 64] = (bf16)(x2 * cs + x1 * sn);
}

// ------------- causal flash attention, swapped-QK, 32x32x16 MFMA -----------
__global__ __launch_bounds__(256, 2) void k_attn(const bf16* __restrict__ Qg,
                                                 const bf16* __restrict__ Kg,
                                                 const bf16* __restrict__ Vg,
                                                 const int* __restrict__ pos,
                                                 bf16* __restrict__ AO) {
  const int bid = blockIdx.x;
  const int slot = bid & 255;
  const int bh = slot & 31;
  const int xch = slot >> 5;
  const int qc = (bid >> 8) ? (15 - xch) : xch;
  const int tid = threadIdx.x, lane = tid & 63, w = tid >> 6;
  const int l31 = lane & 31, h = lane >> 5;
  __shared__ bf16 Ks[2][64 * 128];
  __shared__ bf16 Vt[2][128 * 72];
  const size_t hbase = (size_t)bh * Ssz * Hd;
  const int q0 = qc * 128 + w * 32;
  bf16x8 qf[8];
  {
    const bf16* qp = Qg + hbase + (size_t)(q0 + l31) * Hd + h * 8;
#pragma unroll
    for (int c = 0; c < 8; c++) qf[c] = *(const bf16x8*)(qp + c * 16);
  }
  {
    const float p = (float)pos[(bh >> 4) * Ssz + (q0 + l31)];
#pragma unroll
    for (int c = 0; c < 4; c++) {
#pragma unroll
      for (int j = 0; j < 8; j++) {
        const int i = c * 16 + 8 * h + j;
        const float f = p * exp2f(-(float)i * 0.20762050593046014f);
        float sn, cs;
        sincosf(f, &sn, &cs);
        const float x1 = (float)qf[c][j], x2 = (float)qf[c + 4][j];
        qf[c][j]     = (bf16)(x1 * cs - x2 * sn);
        qf[c + 4][j] = (bf16)(x2 * cs + x1 * sn);
      }
    }
  }
  float m = -1e30f, lsum = 0.f;
  f32x16 o[4] = {};
  const int NT = 2 * (qc + 1);
  const int r4  = (tid >> 4) << 2;
  const int hd0 = (tid & 15) << 3;
  bf16x8 vv[4];
#pragma unroll
  for (int p = 0; p < 4; p++)
    vv[p] = *(const bf16x8*)(Vg + hbase + (size_t)(r4 + p) * Hd + hd0);
  __builtin_amdgcn_sched_barrier(0);
#pragma unroll
  for (int i = 0; i < 4; i++) {
    const int db  = (w * 4 + i) * 1024 + (lane << 4);
    const int row = db >> 8;
    const int cb  = (db & 255) ^ ((row & 7) << 4);
    gload_lds16(Kg + hbase + row * Hd + (cb >> 1), Ks[0] + (w * 4 + i) * 512);
  }
  for (int t = 0; t < NT; ++t) {
    const int kv0 = t * 64;
    const int cur = t & 1;
    asm volatile("s_waitcnt vmcnt(4)" ::: "memory");
#pragma unroll
    for (int j = 0; j < 8; j++) {
      uint2 wv;
      wv.x = pkbf(vv[0][j], vv[1][j]);
      wv.y = pkbf(vv[2][j], vv[3][j]);
      const int hd = hd0 + j;
      const int cb = (r4 * 2) ^ (((hd >> 3) & 7) << 4);
      *(uint2*)((char*)(Vt[cur]) + hd * 144 + cb) = wv;
    }
    const int tn = (t + 1 < NT) ? t + 1 : t;
    const size_t nb = (size_t)tn * 64;
#pragma unroll
    for (int p = 0; p < 4; p++)
      vv[p] = *(const bf16x8*)(Vg + hbase + (nb + r4 + p) * Hd + hd0);
    __builtin_amdgcn_sched_barrier(0);
#pragma unroll
    for (int i = 0; i < 4; i++) {
      const int db  = (w * 4 + i) * 1024 + (lane << 4);
      const int row = db >> 8;
      const int cb  = (db & 255) ^ ((row & 7) << 4);
      gload_lds16(Kg + hbase + (nb + row) * Hd + (cb >> 1), Ks[cur ^ 1] + (w * 4 + i) * 512);
    }
    asm volatile("s_waitcnt vmcnt(8) lgkmcnt(0)" ::: "memory");
    __builtin_amdgcn_sched_barrier(0);
    __builtin_amdgcn_s_barrier();
    if (kv0 <= q0 + 31) {
      const bf16* KsC = Ks[cur];
      const bf16* VtC = Vt[cur];
      f32x16 s0 = {}, s1 = {};
      __builtin_amdgcn_s_setprio(1);
#pragma unroll
      for (int c = 0; c < 8; c++) {
        const int cb = (c * 32 + h * 16) ^ ((l31 & 7) << 4);
        bf16x8 k0 = *(const bf16x8*)((const char*)KsC + l31 * 256 + cb);
        bf16x8 k1 = *(const bf16x8*)((const char*)KsC + (32 + l31) * 256 + cb);
        s0 = __builtin_amdgcn_mfma_f32_32x32x16_bf16(k0, qf[c], s0, 0, 0, 0);
        s1 = __builtin_amdgcn_mfma_f32_32x32x16_bf16(k1, qf[c], s1, 0, 0, 0);
      }
      __builtin_amdgcn_s_setprio(0);
      if (kv0 + 63 > q0) {
        const int qg = q0 + l31;
        const int kb = kv0 + 4 * h;
#pragma unroll
        for (int r = 0; r < 16; r++) {
          const int cr = (r & 3) + 8 * (r >> 2);
          if (kb + cr > qg)      s0[r] = -1e30f;
          if (kb + 32 + cr > qg) s1[r] = -1e30f;
        }
      }
      float tm = s0[0];
#pragma unroll
      for (int r = 1; r < 16; r++) tm = fmaxf(tm, s0[r]);
#pragma unroll
      for (int r = 0; r < 16; r++) tm = fmaxf(tm, s1[r]);
      tm = fmaxf(tm, __shfl_xor(tm, 32));
      if (!__all(tm - m <= 8.0f)) {
        const float mn = fmaxf(m, tm);
        const float rs = exp2f(m - mn);
        m = mn; lsum *= rs;
#pragma unroll
        for (int ct = 0; ct < 4; ct++)
#pragma unroll
          for (int r = 0; r < 16; r++) o[ct][r] *= rs;
      }
      float ps = 0.f;
#pragma unroll
      for (int r = 0; r < 16; r++) { s0[r] = exp2f(s0[r] - m); ps += s0[r]; }
#pragma unroll
      for (int r = 0; r < 16; r++) { s1[r] = exp2f(s1[r] - m); ps += s1[r]; }
      ps += __shfl_xor(ps, 32);
      lsum += ps;
      uint32_t gw[8][2];
#pragma unroll
      for (int g = 0; g < 4; g++) {
        gw[g][0]     = pkff(s0[4 * g], s0[4 * g + 1]);
        gw[g][1]     = pkff(s0[4 * g + 2], s0[4 * g + 3]);
        gw[4 + g][0] = pkff(s1[4 * g], s1[4 * g + 1]);
        gw[4 + g][1] = pkff(s1[4 * g + 2], s1[4 * g + 3]);
      }
#pragma unroll
      for (int kc = 0; kc < 4; kc++) {
        const uint32_t a0 = gw[2 * kc][0], a1 = gw[2 * kc][1];
        const uint32_t b0 = gw[2 * kc + 1][0], b1 = gw[2 * kc + 1][1];
        const uint32_t sd0 = h ? a0 : b0, sd1 = h ? a1 : b1;
        const uint32_t r0 = (uint32_t)__shfl_xor((int)sd0, 32);
        const uint32_t r1 = (uint32_t)__shfl_xor((int)sd1, 32);
        union { uint32_t u[4]; bf16x8 v; } pa;
        pa.u[0] = h ? r0 : a0; pa.u[1] = h ? r1 : a1;
        pa.u[2] = h ? b0 : r0; pa.u[3] = h ? b1 : r1;
        __builtin_amdgcn_s_setprio(1);
#pragma unroll
        for (int ct = 0; ct < 4; ct++) {
          const int row = ct * 32 + l31;
          const int cb = (kc * 32 + h * 16) ^ (((row >> 3) & 7) << 4);
          bf16x8 vf = *(const bf16x8*)((const char*)VtC + row * 144 + cb);
          o[ct] = __builtin_amdgcn_mfma_f32_32x32x16_bf16(pa.v, vf, o[ct], 0, 0, 0);
        }
        __builtin_amdgcn_s_setprio(0);
      }
    }
    __builtin_amdgcn_s_barrier();
  }
  const float linv = 1.0f / lsum;
  float li[16];
#pragma unroll
  for (int r = 0; r < 16; r++)
    li[r] = __shfl(linv, (r & 3) + 8 * (r >> 2) + 4 * h);
  const int b = bh >> 4, hh = bh & 15;
#pragma unroll
  for (int ct = 0; ct < 4; ct++) {
#pragma unroll
    for (int r = 0; r < 16; r++) {
      const int qrow = q0 + (r & 3) + 8 * (r >> 2) + 4 * h;
      AO[((size_t)b * Ssz + qrow) * Hid + hh * Hd + ct * 32 + l31] = (bf16)(o[ct][r] * li[r]);
    }
  }
}

extern "C" void kernel_launch(void* const* d_in, const int* in_sizes, int n_in,
                              void* d_out, int out_size, void* d_ws, size_t ws_size,
                              hipStream_t stream) {
  (void)in_sizes; (void)n_in; (void)out_size; (void)ws_size;
  const float* hidden   = (const float*)d_in[0];
  const int*   positions= (const int*)d_in[1];
  const float* wq = (const float*)d_in[2];
  const float* bq = (const float*)d_in[3];
  const float* wk = (const float*)d_in[4];
  const float* bk = (const float*)d_in[5];
  const float* wv = (const float*)d_in[6];
  const float* bv = (const float*)d_in[7];
  const float* wc = (const float*)d_in[8];
  float* out = (float*)d_out;

  char* ws = (char*)d_ws;
  bf16* WT  = (bf16*)ws;                                               // 4*Hid*Hid bf16 (q,k,v,c)
  bf16* Hbf = (bf16*)(ws + (size_t)4 * Hid * Hid * 2);                 // Mrows*Hid (reused as AO)
  bf16* Qb  = (bf16*)(ws + (size_t)4 * Hid * Hid * 2 + (size_t)Mrows * Hid * 2);
  bf16* Kb  = Qb + (size_t)Mrows * Hid;
  bf16* Vb  = Kb + (size_t)Mrows * Hid;

  k_cvt<<<dim3(Mrows * Hid / 4 / 256), dim3(256), 0, stream>>>(hidden, Hbf, Mrows * Hid / 4);
  k_wtrans<<<dim3(Hid / 64, Hid / 64, 4), dim3(256), 0, stream>>>(wq, wk, wv, wc, WT);
  // fused QKV: m201-port 256x256 tiles, grid 24n x 16m = 384 blocks
  k_qkv<<<dim3(24, 16), dim3(512), 0, stream>>>(
      Hbf, WT, bq, bk, bv, Qb, Kb, Vb);
  // K-only RoPE (Q-rope fused into k_attn)
  k_rope<<<dim3(Bsz * NHd * Ssz * 64 / 256), dim3(256), 0, stream>>>(Kb, positions);
  // balanced 1D attention grid: pair (bid, bid+256) is (x, 15-x)
  k_attn<<<dim3(512), dim3(256), 0, stream>>>(Qb, Kb, Vb, positions, Hbf /*AO*/);
  // output projection: grid 16x16 = 256 blocks = 1.0 exact CU-round
  k_gemm<8, 4><<<dim3(16, 16), dim3(512), 0, stream>>>(
      Hbf, WT + (size_t)3 * Hid * Hid, out);
}

// Round 14
// 260.176 us; speedup vs baseline: 1.1119x; 1.1119x over previous
//
#include <hip/hip_runtime.h>
#include <stdint.h>

constexpr int Bsz = 2;
constexpr int Ssz = 2048;
constexpr int Hid = 2048;
constexpr int NHd = 16;
constexpr int Hd  = 128;
constexpr int Mrows = Bsz * Ssz;                 // 4096

typedef __bf16 bf16;
typedef __bf16 bf16x8 __attribute__((ext_vector_type(8)));
typedef __bf16 bf16x4 __attribute__((ext_vector_type(4)));
typedef float  f32x4  __attribute__((ext_vector_type(4)));
typedef float  f32x16 __attribute__((ext_vector_type(16)));

__device__ __forceinline__ void gload_lds16(const bf16* g, bf16* l) {
  __builtin_amdgcn_global_load_lds((const __attribute__((address_space(1))) void*)g,
                                   (__attribute__((address_space(3))) void*)l, 16, 0, 0);
}

__device__ __forceinline__ uint32_t pkbf(bf16 a, bf16 b) {
  union { bf16 hh[2]; uint32_t u; } x;
  x.hh[0] = a; x.hh[1] = b;
  return x.u;
}
__device__ __forceinline__ uint32_t pkff(float a, float b) {
  return pkbf((bf16)a, (bf16)b);
}

// ------ f32 -> bf16 bulk convert, grid-stride (G11: ~2048 blocks) ----------
__global__ void k_cvt(const float* __restrict__ in, bf16* __restrict__ out, int n4) {
  const int stride = gridDim.x * blockDim.x;
  for (int i = blockIdx.x * blockDim.x + threadIdx.x; i < n4; i += stride) {
    float4 v = ((const float4*)in)[i];
    bf16x4 o = { (bf16)v.x, (bf16)v.y, (bf16)v.z, (bf16)v.w };
    ((bf16x4*)out)[i] = o;
  }
}

// ------- transpose 4 weights [K][N] f32 -> [N][K] bf16, vectorized ---------
__global__ void k_wtrans(const float* __restrict__ w0, const float* __restrict__ w1,
                         const float* __restrict__ w2, const float* __restrict__ w3,
                         bf16* __restrict__ out) {
  __shared__ float tile[64][65];
  const int z = blockIdx.z;
  const float* w = (z == 0) ? w0 : (z == 1) ? w1 : (z == 2) ? w2 : w3;
  bf16* o = out + (size_t)z * Hid * Hid;
  const int n0 = blockIdx.x * 64, k0 = blockIdx.y * 64;
  const int tid = threadIdx.x;
  {
    const int row = tid >> 4, col = (tid & 15) * 4;
#pragma unroll
    for (int i = 0; i < 4; i++) {
      float4 v = *(const float4*)&w[(size_t)(k0 + row + i * 16) * Hid + n0 + col];
      tile[row + i * 16][col + 0] = v.x;
      tile[row + i * 16][col + 1] = v.y;
      tile[row + i * 16][col + 2] = v.z;
      tile[row + i * 16][col + 3] = v.w;
    }
  }
  __syncthreads();
  {
    const int n = tid >> 2, ks = (tid & 3) * 16;
    union { bf16x8 v[2]; bf16 e[16]; } pk;
#pragma unroll
    for (int j = 0; j < 16; j++) pk.e[j] = (bf16)tile[ks + j][n];
    bf16* op = &o[(size_t)(n0 + n) * Hid + k0 + ks];
    *(bf16x8*)op = pk.v[0];
    *(bf16x8*)(op + 8) = pk.v[1];
  }
}

// ---- swizzled-LDS fragment read: element (row,k) lives at byte
//      row*128 + (((k>>3) ^ (row&7))<<4) + (k&7)*2
__device__ __forceinline__ bf16x8 rdfrag(const bf16* t, int row, int kslot) {
  return *(const bf16x8*)((const char*)t + row * 128 + (((kslot ^ (row & 7)) & 7) << 4));
}

// ---- stage a 128-row x 64-col bf16 slice (16 KB): 2 gload_lds per thread
__device__ __forceinline__ void stage_half(const bf16* g, bf16* l, int w, int lane) {
  const int rsub = lane >> 3;
  const int slot = (lane & 7) ^ rsub;
#pragma unroll
  for (int j = 0; j < 2; ++j) {
    const int blk = w * 2 + j;
    gload_lds16(g + (size_t)(blk * 8 + rsub) * Hid + slot * 8, l + blk * 512);
  }
}

// ---- stage a 192-row x 64-col slice (24 KB): 3 gload_lds per thread
__device__ __forceinline__ void stage_192(const bf16* g, bf16* l, int w, int lane) {
  const int rsub = lane >> 3;
  const int slot = (lane & 7) ^ rsub;
#pragma unroll
  for (int j = 0; j < 3; ++j) {
    const int blk = w * 3 + j;
    gload_lds16(g + (size_t)(blk * 8 + rsub) * Hid + slot * 8, l + blk * 512);
  }
}

#define PH_BAR() __builtin_amdgcn_s_barrier()

// ---- QKV GEMM (best measured, R9 structure): 256x192 tile, BK=64, 8 waves
//      (2m x 4n), per-wave 128x48, 3 phases/K-tile x 16 MFMA (P3 reg-only).
//      A dbuf (64 KB) + B triple-buffer (72 KB); counted vmcnt(3) boundary.
__global__ __launch_bounds__(512, 1) void k_qkv(const bf16* __restrict__ A,
                                                const bf16* __restrict__ Bt,
                                                const float* __restrict__ biasq,
                                                const float* __restrict__ biask,
                                                const float* __restrict__ biasv,
                                                bf16* __restrict__ Qo, bf16* __restrict__ Ko,
                                                bf16* __restrict__ Vo) {
  constexpr int KK = Hid;
  constexpr int NT = KK / 64;          // 32 K-tiles
  __shared__ bf16 smA[2][256 * 64];    // 64 KB
  __shared__ bf16 smB[3][192 * 64];    // 72 KB
  const int hw = blockIdx.y * gridDim.x + blockIdx.x;
  const int chunk = hw & 7, within = hw >> 3;
  const int cr = chunk & 1, cc = chunk >> 1;
  const int mt = cr * 8 + (within & 7);
  const int nt = cc * 8 + (within >> 3);
  const int m0 = mt * 256, n0 = nt * 192;
  const int tid = threadIdx.x, lane = tid & 63, w = tid >> 6;
  const int wm = w >> 2, wn = w & 3;
  const int frow = lane & 15, a4 = lane >> 4;
  const bf16* Ag = A + (size_t)m0 * KK;
  const bf16* Bg = Bt + (size_t)n0 * KK;
  f32x4 acc[8][3] = {};
  stage_half(Ag,                    smA[0],            w, lane);
  stage_half(Ag + (size_t)128 * KK, smA[0] + 128 * 64, w, lane);
  stage_192 (Bg,                    smB[0],            w, lane);
  stage_192 (Bg + 64,               smB[1],            w, lane);
  asm volatile("s_waitcnt vmcnt(3)" ::: "memory");
  __builtin_amdgcn_sched_barrier(0);
  __builtin_amdgcn_s_barrier();
  for (int kt = 0; kt < NT; ++kt) {
    const bf16* At  = smA[kt & 1];
    const bf16* Btl = smB[kt % 3];
    const bool more1 = (kt + 1) < NT;
    const bool more2 = (kt + 2) < NT;
    bf16x8 afA[4][2], afB[4][2], bfr[3][2];
#pragma unroll
    for (int f = 0; f < 4; ++f)
#pragma unroll
      for (int kk = 0; kk < 2; ++kk)
        afA[f][kk] = rdfrag(At, wm * 128 + f * 16 + frow, kk * 4 + a4);
#pragma unroll
    for (int nf = 0; nf < 3; ++nf)
#pragma unroll
      for (int kk = 0; kk < 2; ++kk)
        bfr[nf][kk] = rdfrag(Btl, wn * 48 + nf * 16 + frow, kk * 4 + a4);
    if (more1) {
      bf16* As2 = smA[(kt + 1) & 1];
      const size_t kn = (size_t)(kt + 1) * 64;
      stage_half(Ag + kn,                    As2,            w, lane);
      stage_half(Ag + (size_t)128 * KK + kn, As2 + 128 * 64, w, lane);
    }
    PH_BAR();
    __builtin_amdgcn_s_setprio(1);
#pragma unroll
    for (int f = 0; f < 4; ++f)
#pragma unroll
      for (int nf = 0; nf < 2; ++nf)
#pragma unroll
        for (int kk = 0; kk < 2; ++kk)
          acc[f][nf] = __builtin_amdgcn_mfma_f32_16x16x32_bf16(
              afA[f][kk], bfr[nf][kk], acc[f][nf], 0, 0, 0);
    __builtin_amdgcn_s_setprio(0);
    __builtin_amdgcn_s_barrier();
#pragma unroll
    for (int f = 0; f < 4; ++f)
#pragma unroll
      for (int kk = 0; kk < 2; ++kk)
        afB[f][kk] = rdfrag(At, wm * 128 + 64 + f * 16 + frow, kk * 4 + a4);
    if (more2) stage_192(Bg + (size_t)(kt + 2) * 64, smB[(kt + 2) % 3], w, lane);
    PH_BAR();
    __builtin_amdgcn_s_setprio(1);
#pragma unroll
    for (int f = 0; f < 4; ++f)
#pragma unroll
      for (int nf = 0; nf < 2; ++nf)
#pragma unroll
        for (int kk = 0; kk < 2; ++kk)
          acc[4 + f][nf] = __builtin_amdgcn_mfma_f32_16x16x32_bf16(
              afB[f][kk], bfr[nf][kk], acc[4 + f][nf], 0, 0, 0);
    __builtin_amdgcn_s_setprio(0);
    __builtin_amdgcn_s_barrier();
    __builtin_amdgcn_s_setprio(1);
#pragma unroll
    for (int f = 0; f < 4; ++f)
#pragma unroll
      for (int kk = 0; kk < 2; ++kk)
        acc[f][2] = __builtin_amdgcn_mfma_f32_16x16x32_bf16(
            afA[f][kk], bfr[2][kk], acc[f][2], 0, 0, 0);
#pragma unroll
    for (int f = 0; f < 4; ++f)
#pragma unroll
      for (int kk = 0; kk < 2; ++kk)
        acc[4 + f][2] = __builtin_amdgcn_mfma_f32_16x16x32_bf16(
            afB[f][kk], bfr[2][kk], acc[4 + f][2], 0, 0, 0);
    __builtin_amdgcn_s_setprio(0);
    if (more1) {
      if (more2) { asm volatile("s_waitcnt vmcnt(3)" ::: "memory"); }
      else       { asm volatile("s_waitcnt vmcnt(0)" ::: "memory"); }
      __builtin_amdgcn_sched_barrier(0);
    }
    __builtin_amdgcn_s_barrier();
  }
#pragma unroll
  for (int nf = 0; nf < 3; ++nf) {
    const int col = n0 + wn * 48 + nf * 16 + frow;
    const int z = col >> 11;
    const float* bias = (z == 0) ? biasq : (z == 1) ? biask : biasv;
    bf16* o = (z == 0) ? Qo : (z == 1) ? Ko : Vo;
    const float oscale = (z == 1) ? (float)(0.08838834764831845 * 1.4426950408889634) : 1.0f;
    const float bb_ = bias[col & 2047];
    const int h = (col >> 7) & 15, hd = col & (Hd - 1);
#pragma unroll
    for (int mf = 0; mf < 8; ++mf) {
#pragma unroll
      for (int r = 0; r < 4; ++r) {
        const int row = m0 + wm * 128 + mf * 16 + a4 * 4 + r;
        const int bb = row >> 11, ss = row & (Ssz - 1);
        o[(((size_t)bb * NHd + h) * Ssz + ss) * Hd + hd] = (bf16)((acc[mf][nf][r] + bb_) * oscale);
      }
    }
  }
}

// ---- output projection: 256x128 tile, BK=64, per-wave 128x32, 2 phases/
//      K-tile, A dbuf + B triple-buffer, counted vmcnt(2) boundary only.
template <int CHM, int CHN>
__global__ __launch_bounds__(512, 1) void k_gemm(const bf16* __restrict__ A,
                                                 const bf16* __restrict__ Bt,
                                                 float* __restrict__ Fo) {
  constexpr int KK = Hid;
  constexpr int NT = KK / 64;
  __shared__ bf16 smA[2][256 * 64];    // 64 KB
  __shared__ bf16 smB[3][128 * 64];    // 48 KB
  const int hw = blockIdx.y * gridDim.x + blockIdx.x;
  const int chunk = hw & 7, within = hw >> 3;
  const int chunk_rows = gridDim.y / CHM;
  const int cr = chunk % chunk_rows, cc = chunk / chunk_rows;
  const int mt = cr * CHM + within % CHM;
  const int nt = cc * CHN + within / CHM;
  const int m0 = mt * 256, n0 = nt * 128;
  const int tid = threadIdx.x, lane = tid & 63, w = tid >> 6;
  const int wm = w >> 2, wn = w & 3;
  const int frow = lane & 15, a4 = lane >> 4;
  const bf16* Ag = A + (size_t)m0 * KK;
  const bf16* Bg = Bt + (size_t)n0 * KK;
  f32x4 acc[8][2] = {};
  stage_half(Ag,                    smA[0],            w, lane);
  stage_half(Ag + (size_t)128 * KK, smA[0] + 128 * 64, w, lane);
  stage_half(Bg,                    smB[0],            w, lane);
  stage_half(Bg + 64,               smB[1],            w, lane);
  asm volatile("s_waitcnt vmcnt(2)" ::: "memory");
  __builtin_amdgcn_sched_barrier(0);
  __builtin_amdgcn_s_barrier();
  for (int kt = 0; kt < NT; ++kt) {
    const bf16* At  = smA[kt & 1];
    const bf16* Btl = smB[kt % 3];
    const bool more1 = (kt + 1) < NT;
    const bool more2 = (kt + 2) < NT;
    bf16x8 afA[4][2], afB[4][2], bfr[2][2];
#pragma unroll
    for (int f = 0; f < 4; ++f)
#pragma unroll
      for (int kk = 0; kk < 2; ++kk)
        afA[f][kk] = rdfrag(At, wm * 128 + f * 16 + frow, kk * 4 + a4);
#pragma unroll
    for (int nf = 0; nf < 2; ++nf)
#pragma unroll
      for (int kk = 0; kk < 2; ++kk)
        bfr[nf][kk] = rdfrag(Btl, wn * 32 + nf * 16 + frow, kk * 4 + a4);
    if (more1) {
      bf16* As2 = smA[(kt + 1) & 1];
      const size_t kn = (size_t)(kt + 1) * 64;
      stage_half(Ag + kn,                    As2,            w, lane);
      stage_half(Ag + (size_t)128 * KK + kn, As2 + 128 * 64, w, lane);
    }
    PH_BAR();
    __builtin_amdgcn_s_setprio(1);
#pragma unroll
    for (int f = 0; f < 4; ++f)
#pragma unroll
      for (int nf = 0; nf < 2; ++nf)
#pragma unroll
        for (int kk = 0; kk < 2; ++kk)
          acc[f][nf] = __builtin_amdgcn_mfma_f32_16x16x32_bf16(
              afA[f][kk], bfr[nf][kk], acc[f][nf], 0, 0, 0);
    __builtin_amdgcn_s_setprio(0);
    __builtin_amdgcn_s_barrier();
#pragma unroll
    for (int f = 0; f < 4; ++f)
#pragma unroll
      for (int kk = 0; kk < 2; ++kk)
        afB[f][kk] = rdfrag(At, wm * 128 + 64 + f * 16 + frow, kk * 4 + a4);
    if (more2) stage_half(Bg + (size_t)(kt + 2) * 64, smB[(kt + 2) % 3], w, lane);
    PH_BAR();
    __builtin_amdgcn_s_setprio(1);
#pragma unroll
    for (int f = 0; f < 4; ++f)
#pragma unroll
      for (int nf = 0; nf < 2; ++nf)
#pragma unroll
        for (int kk = 0; kk < 2; ++kk)
          acc[4 + f][nf] = __builtin_amdgcn_mfma_f32_16x16x32_bf16(
              afB[f][kk], bfr[nf][kk], acc[4 + f][nf], 0, 0, 0);
    __builtin_amdgcn_s_setprio(0);
    if (more1) {
      if (more2) { asm volatile("s_waitcnt vmcnt(2)" ::: "memory"); }
      else       { asm volatile("s_waitcnt vmcnt(0)" ::: "memory"); }
      __builtin_amdgcn_sched_barrier(0);
    }
    __builtin_amdgcn_s_barrier();
  }
#pragma unroll
  for (int mf = 0; mf < 8; ++mf)
#pragma unroll
    for (int nf = 0; nf < 2; ++nf) {
      const int col = n0 + wn * 32 + nf * 16 + frow;
#pragma unroll
      for (int r = 0; r < 4; ++r) {
        const int row = m0 + wm * 128 + mf * 16 + a4 * 4 + r;
        Fo[(size_t)row * Hid + col] = acc[mf][nf][r];
      }
    }
}

// -------- RoPE (neox) on K only, grid-stride, 1 sincos / 2 elems ----------
__global__ void k_rope(bf16* __restrict__ Kk, const int* __restrict__ pos) {
  const int stride = gridDim.x * blockDim.x;
  const int total = Bsz * NHd * Ssz * 32;           // i in [0,32), pairs (i,i+32)
  for (int idx = blockIdx.x * 256 + threadIdx.x; idx < total; idx += stride) {
    const int i = idx & 31;
    const int s = (idx >> 5) & (Ssz - 1);
    const int bh = idx >> 16;
    const int b = bh >> 4;
    const float p = (float)pos[b * Ssz + s];
    const float f0 = p * exp2f(-(float)i * 0.20762050593046014f);
    const float f1 = p * exp2f(-(float)(i + 32) * 0.20762050593046014f);
    float sn0, cs0, sn1, cs1;
    sincosf(f0, &sn0, &cs0);
    sincosf(f1, &sn1, &cs1);
    const size_t base = ((size_t)bh * Ssz + s) * Hd;
    float x1 = (float)Kk[base + i], x2 = (float)Kk[base + i + 64];
    Kk[base + i]      = (bf16)(x1 * cs0 - x2 * sn0);
    Kk[base + i + 64] = (bf16)(x2 * cs0 + x1 * sn0);
    x1 = (float)Kk[base + i + 32]; x2 = (float)Kk[base + i + 96];
    Kk[base + i + 32] = (bf16)(x1 * cs1 - x2 * sn1);
    Kk[base + i + 96] = (bf16)(x2 * cs1 + x1 * sn1);
  }
}

// ------------- causal flash attention, swapped-QK, 32x32x16 MFMA -----------
// Balanced 1D grid: co-resident pair (bid, bid+256) gets complementary qc
// (x, 15-x). XCD = bh&7 (L2-local). Q-RoPE fused in-register.
__global__ __launch_bounds__(256, 2) void k_attn(const bf16* __restrict__ Qg,
                                                 const bf16* __restrict__ Kg,
                                                 const bf16* __restrict__ Vg,
                                                 const int* __restrict__ pos,
                                                 bf16* __restrict__ AO) {
  const int bid = blockIdx.x;
  const int slot = bid & 255;
  const int bh = slot & 31;
  const int xch = slot >> 5;
  const int qc = (bid >> 8) ? (15 - xch) : xch;
  const int tid = threadIdx.x, lane = tid & 63, w = tid >> 6;
  const int l31 = lane & 31, h = lane >> 5;
  __shared__ bf16 Ks[2][64 * 128];
  __shared__ bf16 Vt[2][128 * 72];
  const size_t hbase = (size_t)bh * Ssz * Hd;
  const int q0 = qc * 128 + w * 32;
  bf16x8 qf[8];
  {
    const bf16* qp = Qg + hbase + (size_t)(q0 + l31) * Hd + h * 8;
#pragma unroll
    for (int c = 0; c < 8; c++) qf[c] = *(const bf16x8*)(qp + c * 16);
  }
  {
    const float p = (float)pos[(bh >> 4) * Ssz + (q0 + l31)];
#pragma unroll
    for (int c = 0; c < 4; c++) {
#pragma unroll
      for (int j = 0; j < 8; j++) {
        const int i = c * 16 + 8 * h + j;
        const float f = p * exp2f(-(float)i * 0.20762050593046014f);
        float sn, cs;
        sincosf(f, &sn, &cs);
        const float x1 = (float)qf[c][j], x2 = (float)qf[c + 4][j];
        qf[c][j]     = (bf16)(x1 * cs - x2 * sn);
        qf[c + 4][j] = (bf16)(x2 * cs + x1 * sn);
      }
    }
  }
  float m = -1e30f, lsum = 0.f;
  f32x16 o[4] = {};
  const int NT = 2 * (qc + 1);
  const int r4  = (tid >> 4) << 2;
  const int hd0 = (tid & 15) << 3;
  bf16x8 vv[4];
#pragma unroll
  for (int p = 0; p < 4; p++)
    vv[p] = *(const bf16x8*)(Vg + hbase + (size_t)(r4 + p) * Hd + hd0);
  __builtin_amdgcn_sched_barrier(0);
#pragma unroll
  for (int i = 0; i < 4; i++) {
    const int db  = (w * 4 + i) * 1024 + (lane << 4);
    const int row = db >> 8;
    const int cb  = (db & 255) ^ ((row & 7) << 4);
    gload_lds16(Kg + hbase + row * Hd + (cb >> 1), Ks[0] + (w * 4 + i) * 512);
  }
  for (int t = 0; t < NT; ++t) {
    const int kv0 = t * 64;
    const int cur = t & 1;
    asm volatile("s_waitcnt vmcnt(4)" ::: "memory");
#pragma unroll
    for (int j = 0; j < 8; j++) {
      uint2 wv;
      wv.x = pkbf(vv[0][j], vv[1][j]);
      wv.y = pkbf(vv[2][j], vv[3][j]);
      const int hd = hd0 + j;
      const int cb = (r4 * 2) ^ (((hd >> 3) & 7) << 4);
      *(uint2*)((char*)(Vt[cur]) + hd * 144 + cb) = wv;
    }
    const int tn = (t + 1 < NT) ? t + 1 : t;
    const size_t nb = (size_t)tn * 64;
#pragma unroll
    for (int p = 0; p < 4; p++)
      vv[p] = *(const bf16x8*)(Vg + hbase + (nb + r4 + p) * Hd + hd0);
    __builtin_amdgcn_sched_barrier(0);
#pragma unroll
    for (int i = 0; i < 4; i++) {
      const int db  = (w * 4 + i) * 1024 + (lane << 4);
      const int row = db >> 8;
      const int cb  = (db & 255) ^ ((row & 7) << 4);
      gload_lds16(Kg + hbase + (nb + row) * Hd + (cb >> 1), Ks[cur ^ 1] + (w * 4 + i) * 512);
    }
    asm volatile("s_waitcnt vmcnt(8) lgkmcnt(0)" ::: "memory");
    __builtin_amdgcn_sched_barrier(0);
    __builtin_amdgcn_s_barrier();
    if (kv0 <= q0 + 31) {
      const bf16* KsC = Ks[cur];
      const bf16* VtC = Vt[cur];
      f32x16 s0 = {}, s1 = {};
      __builtin_amdgcn_s_setprio(1);
#pragma unroll
      for (int c = 0; c < 8; c++) {
        const int cb = (c * 32 + h * 16) ^ ((l31 & 7) << 4);
        bf16x8 k0 = *(const bf16x8*)((const char*)KsC + l31 * 256 + cb);
        bf16x8 k1 = *(const bf16x8*)((const char*)KsC + (32 + l31) * 256 + cb);
        s0 = __builtin_amdgcn_mfma_f32_32x32x16_bf16(k0, qf[c], s0, 0, 0, 0);
        s1 = __builtin_amdgcn_mfma_f32_32x32x16_bf16(k1, qf[c], s1, 0, 0, 0);
      }
      __builtin_amdgcn_s_setprio(0);
      if (kv0 + 63 > q0) {
        const int qg = q0 + l31;
        const int kb = kv0 + 4 * h;
#pragma unroll
        for (int r = 0; r < 16; r++) {
          const int cr = (r & 3) + 8 * (r >> 2);
          if (kb + cr > qg)      s0[r] = -1e30f;
          if (kb + 32 + cr > qg) s1[r] = -1e30f;
        }
      }
      float tm = s0[0];
#pragma unroll
      for (int r = 1; r < 16; r++) tm = fmaxf(tm, s0[r]);
#pragma unroll
      for (int r = 0; r < 16; r++) tm = fmaxf(tm, s1[r]);
      tm = fmaxf(tm, __shfl_xor(tm, 32));
      if (!__all(tm - m <= 8.0f)) {
        const float mn = fmaxf(m, tm);
        const float rs = exp2f(m - mn);
        m = mn; lsum *= rs;
#pragma unroll
        for (int ct = 0; ct < 4; ct++)
#pragma unroll
          for (int r = 0; r < 16; r++) o[ct][r] *= rs;
      }
      float ps = 0.f;
#pragma unroll
      for (int r = 0; r < 16; r++) { s0[r] = exp2f(s0[r] - m); ps += s0[r]; }
#pragma unroll
      for (int r = 0; r < 16; r++) { s1[r] = exp2f(s1[r] - m); ps += s1[r]; }
      ps += __shfl_xor(ps, 32);
      lsum += ps;
      uint32_t gw[8][2];
#pragma unroll
      for (int g = 0; g < 4; g++) {
        gw[g][0]     = pkff(s0[4 * g], s0[4 * g + 1]);
        gw[g][1]     = pkff(s0[4 * g + 2], s0[4 * g + 3]);
        gw[4 + g][0] = pkff(s1[4 * g], s1[4 * g + 1]);
        gw[4 + g][1] = pkff(s1[4 * g + 2], s1[4 * g + 3]);
      }
#pragma unroll
      for (int kc = 0; kc < 4; kc++) {
        const uint32_t a0 = gw[2 * kc][0], a1 = gw[2 * kc][1];
        const uint32_t b0 = gw[2 * kc + 1][0], b1 = gw[2 * kc + 1][1];
        const uint32_t sd0 = h ? a0 : b0, sd1 = h ? a1 : b1;
        const uint32_t r0 = (uint32_t)__shfl_xor((int)sd0, 32);
        const uint32_t r1 = (uint32_t)__shfl_xor((int)sd1, 32);
        union { uint32_t u[4]; bf16x8 v; } pa;
        pa.u[0] = h ? r0 : a0; pa.u[1] = h ? r1 : a1;
        pa.u[2] = h ? b0 : r0; pa.u[3] = h ? b1 : r1;
        __builtin_amdgcn_s_setprio(1);
#pragma unroll
        for (int ct = 0; ct < 4; ct++) {
          const int row = ct * 32 + l31;
          const int cb = (kc * 32 + h * 16) ^ (((row >> 3) & 7) << 4);
          bf16x8 vf = *(const bf16x8*)((const char*)VtC + row * 144 + cb);
          o[ct] = __builtin_amdgcn_mfma_f32_32x32x16_bf16(pa.v, vf, o[ct], 0, 0, 0);
        }
        __builtin_amdgcn_s_setprio(0);
      }
    }
    __builtin_amdgcn_s_barrier();
  }
  const float linv = 1.0f / lsum;
  float li[16];
#pragma unroll
  for (int r = 0; r < 16; r++)
    li[r] = __shfl(linv, (r & 3) + 8 * (r >> 2) + 4 * h);
  const int b = bh >> 4, hh = bh & 15;
#pragma unroll
  for (int ct = 0; ct < 4; ct++) {
#pragma unroll
    for (int r = 0; r < 16; r++) {
      const int qrow = q0 + (r & 3) + 8 * (r >> 2) + 4 * h;
      AO[((size_t)b * Ssz + qrow) * Hid + hh * Hd + ct * 32 + l31] = (bf16)(o[ct][r] * li[r]);
    }
  }
}

extern "C" void kernel_launch(void* const* d_in, const int* in_sizes, int n_in,
                              void* d_out, int out_size, void* d_ws, size_t ws_size,
                              hipStream_t stream) {
  (void)in_sizes; (void)n_in; (void)out_size; (void)ws_size;
  const float* hidden   = (const float*)d_in[0];
  const int*   positions= (const int*)d_in[1];
  const float* wq = (const float*)d_in[2];
  const float* bq = (const float*)d_in[3];
  const float* wk = (const float*)d_in[4];
  const float* bk = (const float*)d_in[5];
  const float* wv = (const float*)d_in[6];
  const float* bv = (const float*)d_in[7];
  const float* wc = (const float*)d_in[8];
  float* out = (float*)d_out;

  char* ws = (char*)d_ws;
  bf16* WT  = (bf16*)ws;                                               // 4*Hid*Hid bf16 (q,k,v,c)
  bf16* Hbf = (bf16*)(ws + (size_t)4 * Hid * Hid * 2);                 // Mrows*Hid (reused as AO)
  bf16* Qb  = (bf16*)(ws + (size_t)4 * Hid * Hid * 2 + (size_t)Mrows * Hid * 2);
  bf16* Kb  = Qb + (size_t)Mrows * Hid;
  bf16* Vb  = Kb + (size_t)Mrows * Hid;

  // grid-stride (G11): 2048 blocks
  k_cvt<<<dim3(2048), dim3(256), 0, stream>>>(hidden, Hbf, Mrows * Hid / 4);
  k_wtrans<<<dim3(Hid / 64, Hid / 64, 4), dim3(256), 0, stream>>>(wq, wk, wv, wc, WT);
  // fused QKV: 256x192 tiles, grid 32n x 16m = 512 blocks = 2.0 exact rounds
  k_qkv<<<dim3(32, 16), dim3(512), 0, stream>>>(
      Hbf, WT, bq, bk, bv, Qb, Kb, Vb);
  // K-only RoPE, grid-stride 2048 blocks
  k_rope<<<dim3(2048), dim3(256), 0, stream>>>(Kb, positions);
  // balanced 1D attention grid: pair (bid, bid+256) is (x, 15-x)
  k_attn<<<dim3(512), dim3(256), 0, stream>>>(Qb, Kb, Vb, positions, Hbf /*AO*/);
  // output projection: grid 16x16 = 256 blocks = 1.0 exact CU-round
  k_gemm<8, 4><<<dim3(16, 16), dim3(512), 0, stream>>>(
      Hbf, WT + (size_t)3 * Hid * Hid, out);
}